// Round 10
// baseline (917.303 us; speedup 1.0000x reference)
//
#include <hip/hip_runtime.h>
#include <math.h>

#define NB   2048   // batch
#define NSEQ 65     // sequence incl. origin
#define ND   256    // IN_DIM (K)
#define NH   8      // heads
#define NL   256    // L
#define NS   64     // walk length (S-1)
#define APAD 264    // padded A row (aux kernels only)

typedef _Float16 f16;
typedef _Float16 f16x4 __attribute__((ext_vector_type(4)));
typedef _Float16 f16x8 __attribute__((ext_vector_type(8)));
typedef float    f32x4 __attribute__((ext_vector_type(4)));

__device__ __forceinline__ float sigmoidf_(float x) {
    return __builtin_amdgcn_rcpf(1.0f + __expf(-x));
}

// ---------------------------------------------------------------------------
// Prep: x walk rows -> xh[b][s][k] f16 (k contiguous), s=0..63 maps x[b][1+s]
// ---------------------------------------------------------------------------
__global__ __launch_bounds__(256) void xh_kernel(const float* __restrict__ x,
                                                 f16* __restrict__ xh) {
    int flat8 = blockIdx.x * 256 + threadIdx.x;   // one f16x8 per thread
    int b  = flat8 >> 11;
    int rm = flat8 & 2047;
    int s  = rm >> 5;
    int k8 = rm & 31;
    const float* src = x + (size_t)b * (NSEQ * ND) + (1 + s) * ND + k8 * 8;
    float4 v0 = *(const float4*)(src);
    float4 v1 = *(const float4*)(src + 4);
    f16x8 o = {(f16)v0.x, (f16)v0.y, (f16)v0.z, (f16)v0.w,
               (f16)v1.x, (f16)v1.y, (f16)v1.z, (f16)v1.w};
    *(f16x8*)(xh + (size_t)b * 16384 + s * 256 + k8 * 8) = o;
}

// ---------------------------------------------------------------------------
// Prep: Wq/Wv/Wk (H,K,N) f32 -> wh[(h*3+m)][n][k] f16 (k contiguous), m=q,v,k
// ---------------------------------------------------------------------------
__global__ __launch_bounds__(256) void wh_kernel(const float* __restrict__ Wq,
                                                 const float* __restrict__ Wv,
                                                 const float* __restrict__ Wk,
                                                 f16* __restrict__ wh) {
    int hm = blockIdx.x >> 4;            // h*3+m, 24 values
    int h  = hm / 3, m = hm % 3;
    int n  = ((blockIdx.x & 15) << 4) + (threadIdx.x >> 4);
    int kc = (threadIdx.x & 15) << 4;
    const float* src = (m == 0 ? Wq : (m == 1 ? Wv : Wk)) + h * (ND * NL);
    f16x8 t0, t1;
    #pragma unroll
    for (int j = 0; j < 8; ++j) t0[j] = (f16)src[(kc + j) * NL + n];
    #pragma unroll
    for (int j = 0; j < 8; ++j) t1[j] = (f16)src[(kc + 8 + j) * NL + n];
    f16* dst = wh + ((size_t)(hm * 256 + n)) * 256 + kc;
    *(f16x8*)dst       = t0;
    *(f16x8*)(dst + 8) = t1;
}

// ---------------------------------------------------------------------------
// Prep: O (2048,256) f32 -> OT[n][k] f16 (k contiguous)
// ---------------------------------------------------------------------------
__global__ __launch_bounds__(256) void ot_kernel(const float* __restrict__ O,
                                                 f16* __restrict__ OT) {
    int n = blockIdx.x;
    int t = threadIdx.x;
    f16x8 v;
    #pragma unroll
    for (int j = 0; j < 8; ++j) v[j] = (f16)O[(size_t)(t * 8 + j) * 256 + n];
    *(f16x8*)(OT + (size_t)n * 2048 + t * 8) = v;
}

// ---------------------------------------------------------------------------
// PKT[h][l][s] = P[s]·Wk[h][:,l]  (transposed: epilogue reads float4 over s)
// ---------------------------------------------------------------------------
__global__ __launch_bounds__(256) void pkt_kernel(const float* __restrict__ P,
                                                  const float* __restrict__ Wk,
                                                  float* __restrict__ PKT) {
    int h = blockIdx.x >> 6;
    int s = blockIdx.x & 63;
    int t = threadIdx.x;
    __shared__ float p_s[ND];
    p_s[t] = P[s * ND + t];
    __syncthreads();
    const float* wk = Wk + h * (ND * NL) + t;
    float acc = 0.f;
    #pragma unroll 8
    for (int d = 0; d < ND; ++d) acc = fmaf(p_s[d], wk[d * NL], acc);
    PKT[((size_t)h * NL + t) * NS + s] = acc;
}

// ---------------------------------------------------------------------------
// OK[h][b][l] = origin_b · Wk[h][:,l]  as f16 MFMA GEMM
// ---------------------------------------------------------------------------
__global__ __launch_bounds__(256) void ok_gemm(const float* __restrict__ x,
                                               const f16*   __restrict__ wh,
                                               float* __restrict__ OK) {
    int mblk = blockIdx.x >> 4;          // 32
    int nblk = blockIdx.x & 15;          // 16
    int b0 = mblk * 64;
    int h  = nblk >> 1;
    int l0 = (nblk & 1) * 128;
    int t = threadIdx.x;
    int w = t >> 6, lane = t & 63, c = lane & 15, g = lane >> 4;

    __shared__ f16 Ao[64 * APAD];
    #pragma unroll
    for (int it = 0; it < 16; ++it) {
        int idx4 = it * 256 + t;
        int s = idx4 >> 6, kq = idx4 & 63;
        float4 v = *(const float4*)(x + (size_t)(b0 + s) * (NSEQ * ND) + kq * 4);
        *(f16x4*)(&Ao[s * APAD + kq * 4]) = (f16x4){(f16)v.x, (f16)v.y, (f16)v.z, (f16)v.w};
    }
    __syncthreads();

    f32x4 acc[4][2];
    #pragma unroll
    for (int mt = 0; mt < 4; ++mt)
        #pragma unroll
        for (int nt = 0; nt < 2; ++nt) acc[mt][nt] = (f32x4){0.f, 0.f, 0.f, 0.f};

    const f16* bb = wh + ((size_t)((h * 3 + 2) * 256 + l0 + w * 32 + c)) * 256;
    #pragma unroll 2
    for (int kk = 0; kk < 8; ++kk) {
        int k0 = kk * 32 + g * 8;
        f16x8 af[4];
        #pragma unroll
        for (int mt = 0; mt < 4; ++mt)
            af[mt] = *(const f16x8*)(&Ao[(mt * 16 + c) * APAD + k0]);
        #pragma unroll
        for (int nt = 0; nt < 2; ++nt) {
            f16x8 bf = *(const f16x8*)(bb + nt * 16 * 256 + k0);
            #pragma unroll
            for (int mt = 0; mt < 4; ++mt)
                acc[mt][nt] = __builtin_amdgcn_mfma_f32_16x16x32_f16(af[mt], bf, acc[mt][nt], 0, 0, 0);
        }
    }
    #pragma unroll
    for (int mt = 0; mt < 4; ++mt)
        #pragma unroll
        for (int nt = 0; nt < 2; ++nt)
            #pragma unroll
            for (int r = 0; r < 4; ++r)
                OK[((size_t)h * NB + b0 + mt * 16 + g * 4 + r) * NL + l0 + w * 32 + nt * 16 + c]
                    = acc[mt][nt][r];
}

// ---------------------------------------------------------------------------
// Main fused kernel: NO LDS AT ALL. One block/batch; wave-private heads.
// A-fragments (walk tile, f16) live in 128 VGPRs, loaded once from xh.
// Per head: 8 chunks of 32 l-cols q-GEMM+edge -> in-wave softmax ->
// 8 chunks v-GEMM+weighted sum -> res. Zero barriers, zero LDS traffic.
// ---------------------------------------------------------------------------
__global__ __launch_bounds__(256, 2) void attn_mfma(
        const f16*   __restrict__ xh,
        const f16*   __restrict__ wh,
        const float* __restrict__ W,
        const float* __restrict__ PKT,
        const float* __restrict__ OK,
        f16* __restrict__ res) {
    int b = blockIdx.x;
    int t = threadIdx.x;
    int w    = t >> 6;
    int lane = t & 63;
    int c = lane & 15;
    int g = lane >> 4;

    // --- A fragments in registers: af[mt][kk] = xh[b][mt*16+c][kk*32+g*8] --
    f16x8 af[4][8];
    const f16* xb = xh + (size_t)b * 16384 + c * 256 + g * 8;
    #pragma unroll
    for (int mt = 0; mt < 4; ++mt)
        #pragma unroll
        for (int kk = 0; kk < 8; ++kk)
            af[mt][kk] = *(const f16x8*)(xb + mt * 16 * 256 + kk * 32);

    int rot  = b & 7;                    // chunk-phase rotation (decorrelate blocks)
    int hrot = (b >> 3) & 1;

    #pragma unroll
    for (int hh = 0; hh < 2; ++hh) {
        int h = w * 2 + ((hh + hrot) & 1);

        // ---- pass 1: q-GEMM + edge, 8 chunks of 32 l-cols ----------------
        float part[4][4];                // [mt][r] -> s = mt*16 + g*4 + r
        #pragma unroll
        for (int mt = 0; mt < 4; ++mt)
            #pragma unroll
            for (int r = 0; r < 4; ++r) part[mt][r] = 0.f;

        for (int ci = 0; ci < 8; ++ci) {
            int ch = (ci + rot) & 7;
            f32x4 acc[4][2];
            #pragma unroll
            for (int mt = 0; mt < 4; ++mt)
                #pragma unroll
                for (int nt = 0; nt < 2; ++nt) acc[mt][nt] = (f32x4){0.f, 0.f, 0.f, 0.f};

            const f16* bq = wh + ((size_t)((h * 3 + 0) * 256 + ch * 32 + c)) * 256 + g * 8;
            #pragma unroll
            for (int kk = 0; kk < 8; ++kk) {
                #pragma unroll
                for (int nt = 0; nt < 2; ++nt) {
                    f16x8 bf = *(const f16x8*)(bq + nt * 16 * 256 + kk * 32);
                    #pragma unroll
                    for (int mt = 0; mt < 4; ++mt)
                        acc[mt][nt] = __builtin_amdgcn_mfma_f32_16x16x32_f16(af[mt][kk], bf, acc[mt][nt], 0, 0, 0);
                }
            }
            // edge for this chunk (bias omitted: softmax-invariant shift)
            #pragma unroll
            for (int nt = 0; nt < 2; ++nt) {
                int l = ch * 32 + nt * 16 + c;
                float wl  = W[h * NL + l];
                float okv = OK[((size_t)h * NB + b) * NL + l];
                const float* pkcol = PKT + ((size_t)h * NL + l) * NS + g * 4;
                #pragma unroll
                for (int mt = 0; mt < 4; ++mt) {
                    float4 pk4 = *(const float4*)(pkcol + mt * 16);
                    float pks[4] = {pk4.x, pk4.y, pk4.z, pk4.w};
                    #pragma unroll
                    for (int r = 0; r < 4; ++r) {
                        float qs = sigmoidf_(acc[mt][nt][r]);
                        float ks = sigmoidf_(okv + pks[r]);
                        part[mt][r] = fmaf(__cosf(ks * qs), wl, part[mt][r]);
                    }
                }
            }
        }

        // ---- in-wave score reduction over c, then softmax over 64 s ------
        #pragma unroll
        for (int mt = 0; mt < 4; ++mt)
            #pragma unroll
            for (int r = 0; r < 4; ++r) {
                float v = part[mt][r];
                v += __shfl_xor(v, 1, 64);
                v += __shfl_xor(v, 2, 64);
                v += __shfl_xor(v, 4, 64);
                v += __shfl_xor(v, 8, 64);
                part[mt][r] = v;         // score[s], uniform over c
            }
        float m = part[0][0];
        #pragma unroll
        for (int mt = 0; mt < 4; ++mt)
            #pragma unroll
            for (int r = 0; r < 4; ++r) m = fmaxf(m, part[mt][r]);
        m = fmaxf(m, __shfl_xor(m, 16, 64));
        m = fmaxf(m, __shfl_xor(m, 32, 64));
        float ssum = 0.f;
        #pragma unroll
        for (int mt = 0; mt < 4; ++mt)
            #pragma unroll
            for (int r = 0; r < 4; ++r) {
                float e = __expf(part[mt][r] - m);
                part[mt][r] = e;
                ssum += e;
            }
        ssum += __shfl_xor(ssum, 16, 64);
        ssum += __shfl_xor(ssum, 32, 64);
        float rinv = __builtin_amdgcn_rcpf(ssum);
        #pragma unroll
        for (int mt = 0; mt < 4; ++mt)
            #pragma unroll
            for (int r = 0; r < 4; ++r) part[mt][r] *= rinv;   // p_s

        // ---- pass 2: v-GEMM + weighted sigmoid sum, 8 chunks -------------
        for (int ci = 0; ci < 8; ++ci) {
            int ch = (ci + rot) & 7;
            f32x4 acc[4][2];
            #pragma unroll
            for (int mt = 0; mt < 4; ++mt)
                #pragma unroll
                for (int nt = 0; nt < 2; ++nt) acc[mt][nt] = (f32x4){0.f, 0.f, 0.f, 0.f};

            const f16* bv = wh + ((size_t)((h * 3 + 1) * 256 + ch * 32 + c)) * 256 + g * 8;
            #pragma unroll
            for (int kk = 0; kk < 8; ++kk) {
                #pragma unroll
                for (int nt = 0; nt < 2; ++nt) {
                    f16x8 bf = *(const f16x8*)(bv + nt * 16 * 256 + kk * 32);
                    #pragma unroll
                    for (int mt = 0; mt < 4; ++mt)
                        acc[mt][nt] = __builtin_amdgcn_mfma_f32_16x16x32_f16(af[mt][kk], bf, acc[mt][nt], 0, 0, 0);
                }
            }
            #pragma unroll
            for (int nt = 0; nt < 2; ++nt) {
                float v = 0.f;
                #pragma unroll
                for (int mt = 0; mt < 4; ++mt)
                    #pragma unroll
                    for (int r = 0; r < 4; ++r)
                        v = fmaf(part[mt][r], sigmoidf_(acc[mt][nt][r]), v);
                v += __shfl_xor(v, 16, 64);
                v += __shfl_xor(v, 32, 64);
                if (g == 0)
                    res[(size_t)b * 2048 + h * NL + ch * 32 + nt * 16 + c] = (f16)v;
            }
        }
    }
}

// ---------------------------------------------------------------------------
// out GEMM: out[b][0:256] = sigmoid(res[b] @ O)  (f16 MFMA, K=2048)
// 128 blocks: 32-row x 128-col tiles (better CU utilization than 64 blocks).
// ---------------------------------------------------------------------------
__global__ __launch_bounds__(256) void out_gemm(
        const float* __restrict__ x,
        const f16*   __restrict__ res,
        const f16*   __restrict__ OT,
        float* __restrict__ out) {
    int mblk = blockIdx.x >> 1;          // 64 tiles of 32 rows
    int nblk = blockIdx.x & 1;           // 2 tiles of 128 cols
    int b0 = mblk * 32;
    int t  = threadIdx.x;
    int w    = t >> 6;
    int lane = t & 63;
    int c = lane & 15;
    int g = lane >> 4;

    __shared__ f16 Ao[32 * APAD];

    f32x4 acc[2][2];
    #pragma unroll
    for (int mt = 0; mt < 2; ++mt)
        #pragma unroll
        for (int nt = 0; nt < 2; ++nt) acc[mt][nt] = (f32x4){0.f, 0.f, 0.f, 0.f};

    for (int chunk = 0; chunk < 8; ++chunk) {
        int kbase = chunk * 256;
        __syncthreads();
        #pragma unroll
        for (int it = 0; it < 4; ++it) {
            int id  = it * 256 + t;
            int row = id >> 5;
            int kc  = (id & 31) << 3;
            *(f16x8*)(&Ao[row * APAD + kc]) =
                *(const f16x8*)(res + (size_t)(b0 + row) * 2048 + kbase + kc);
        }
        __syncthreads();
        #pragma unroll
        for (int kk = 0; kk < 8; ++kk) {
            int k0 = kk * 32 + g * 8;
            f16x8 af[2];
            #pragma unroll
            for (int mt = 0; mt < 2; ++mt)
                af[mt] = *(const f16x8*)(&Ao[(mt * 16 + c) * APAD + k0]);
            #pragma unroll
            for (int nt = 0; nt < 2; ++nt) {
                f16x8 bf = *(const f16x8*)(OT + (size_t)(nblk * 128 + w * 32 + nt * 16 + c) * 2048 + kbase + k0);
                #pragma unroll
                for (int mt = 0; mt < 2; ++mt)
                    acc[mt][nt] = __builtin_amdgcn_mfma_f32_16x16x32_f16(af[mt], bf, acc[mt][nt], 0, 0, 0);
            }
        }
    }
    #pragma unroll
    for (int mt = 0; mt < 2; ++mt)
        #pragma unroll
        for (int nt = 0; nt < 2; ++nt)
            #pragma unroll
            for (int r = 0; r < 4; ++r) {
                int row = mt * 16 + g * 4 + r;
                int col = nblk * 128 + w * 32 + nt * 16 + c;
                out[(size_t)(b0 + row) * 512 + col] = sigmoidf_(acc[mt][nt][r]);
            }
    if (nblk == 1) {                     // origin passthrough for these 32 rows
        for (int r2 = 0; r2 < 32; ++r2)
            out[(size_t)(b0 + r2) * 512 + 256 + t] = x[(size_t)(b0 + r2) * (NSEQ * ND) + t];
    }
}

// ---------------------------------------------------------------------------
extern "C" void kernel_launch(void* const* d_in, const int* in_sizes, int n_in,
                              void* d_out, int out_size, void* d_ws, size_t ws_size,
                              hipStream_t stream) {
    const float* x    = (const float*)d_in[0];
    const float* Wq   = (const float*)d_in[1];
    const float* Wk   = (const float*)d_in[2];
    const float* Wv   = (const float*)d_in[3];
    const float* W    = (const float*)d_in[4];
    const float* O    = (const float*)d_in[5];
    const float* P    = (const float*)d_in[6];
    // d_in[7] = bias: unused — softmax is invariant to the bias*sum(W) shift
    float* out = (float*)d_out;

    // ws carve: wh 3MB | OT 1MB | PKT 512KB | OK 16MB | res 8MB | xh 32MB
    char* wsb = (char*)d_ws;
    f16*   wh  = (f16*)wsb;                       // 3*8*256*256 f16 = 3145728 B
    f16*   OT  = (f16*)(wsb + 3145728);           // 256*2048 f16   = 1048576 B
    float* PKT = (float*)(wsb + 4194304);         // 8*256*64 f32   = 524288 B
    float* OK  = (float*)(wsb + 4718592);         // 8*2048*256 f32 = 16777216 B
    f16*   res = (f16*)(wsb + 21495808);          // 2048*2048 f16  = 8388608 B
    f16*   xh  = (f16*)(wsb + 29884416);          // 2048*64*256 f16 = 33554432 B

    xh_kernel<<<16384, 256, 0, stream>>>(x, xh);
    wh_kernel<<<384, 256, 0, stream>>>(Wq, Wv, Wk, wh);
    ot_kernel<<<256, 256, 0, stream>>>(O, OT);
    pkt_kernel<<<NH * NS, 256, 0, stream>>>(P, Wk, PKT);
    ok_gemm<<<512, 256, 0, stream>>>(x, wh, OK);
    attn_mfma<<<NB, 256, 0, stream>>>(xh, wh, W, PKT, OK, res);
    out_gemm<<<128, 256, 0, stream>>>(x, res, OT, out);
}

// Round 11
// 874.382 us; speedup vs baseline: 1.0491x; 1.0491x over previous
//
#include <hip/hip_runtime.h>
#include <math.h>

#define NB   2048   // batch
#define NSEQ 65     // sequence incl. origin
#define ND   256    // IN_DIM (K)
#define NH   8      // heads
#define NL   256    // L
#define NS   64     // walk length (S-1)
#define APAD 264    // padded A row (aux kernels only)

typedef _Float16 f16;
typedef _Float16 f16x4 __attribute__((ext_vector_type(4)));
typedef _Float16 f16x8 __attribute__((ext_vector_type(8)));
typedef float    f32x4 __attribute__((ext_vector_type(4)));

__device__ __forceinline__ float sigmoidf_(float x) {
    return __builtin_amdgcn_rcpf(1.0f + __expf(-x));
}
// cos for x in [0,1]: v_cos takes revolutions, no range reduction needed
__device__ __forceinline__ float cos01_(float x) {
    return __builtin_amdgcn_cosf(x * 0.15915494309189535f);
}

// ---------------------------------------------------------------------------
// Prep: x walk rows -> xh[b][s][k] f16 (k contiguous), s=0..63 maps x[b][1+s]
// ---------------------------------------------------------------------------
__global__ __launch_bounds__(256) void xh_kernel(const float* __restrict__ x,
                                                 f16* __restrict__ xh) {
    int flat8 = blockIdx.x * 256 + threadIdx.x;   // one f16x8 per thread
    int b  = flat8 >> 11;
    int rm = flat8 & 2047;
    int s  = rm >> 5;
    int k8 = rm & 31;
    const float* src = x + (size_t)b * (NSEQ * ND) + (1 + s) * ND + k8 * 8;
    float4 v0 = *(const float4*)(src);
    float4 v1 = *(const float4*)(src + 4);
    f16x8 o = {(f16)v0.x, (f16)v0.y, (f16)v0.z, (f16)v0.w,
               (f16)v1.x, (f16)v1.y, (f16)v1.z, (f16)v1.w};
    *(f16x8*)(xh + (size_t)b * 16384 + s * 256 + k8 * 8) = o;
}

// ---------------------------------------------------------------------------
// Prep: Wq/Wv/Wk (H,K,N) f32 -> wh[(h*3+m)][n][k] f16 (k contiguous), m=q,v,k
// ---------------------------------------------------------------------------
__global__ __launch_bounds__(256) void wh_kernel(const float* __restrict__ Wq,
                                                 const float* __restrict__ Wv,
                                                 const float* __restrict__ Wk,
                                                 f16* __restrict__ wh) {
    int hm = blockIdx.x >> 4;            // h*3+m, 24 values
    int h  = hm / 3, m = hm % 3;
    int n  = ((blockIdx.x & 15) << 4) + (threadIdx.x >> 4);
    int kc = (threadIdx.x & 15) << 4;
    const float* src = (m == 0 ? Wq : (m == 1 ? Wv : Wk)) + h * (ND * NL);
    f16x8 t0, t1;
    #pragma unroll
    for (int j = 0; j < 8; ++j) t0[j] = (f16)src[(kc + j) * NL + n];
    #pragma unroll
    for (int j = 0; j < 8; ++j) t1[j] = (f16)src[(kc + 8 + j) * NL + n];
    f16* dst = wh + ((size_t)(hm * 256 + n)) * 256 + kc;
    *(f16x8*)dst       = t0;
    *(f16x8*)(dst + 8) = t1;
}

// ---------------------------------------------------------------------------
// Prep: O (2048,256) f32 -> OT[n][k] f16 (k contiguous)
// ---------------------------------------------------------------------------
__global__ __launch_bounds__(256) void ot_kernel(const float* __restrict__ O,
                                                 f16* __restrict__ OT) {
    int n = blockIdx.x;
    int t = threadIdx.x;
    f16x8 v;
    #pragma unroll
    for (int j = 0; j < 8; ++j) v[j] = (f16)O[(size_t)(t * 8 + j) * 256 + n];
    *(f16x8*)(OT + (size_t)n * 2048 + t * 8) = v;
}

// ---------------------------------------------------------------------------
// PKT[h][l][s] = P[s]·Wk[h][:,l]  (transposed: epilogue reads float4 over s)
// ---------------------------------------------------------------------------
__global__ __launch_bounds__(256) void pkt_kernel(const float* __restrict__ P,
                                                  const float* __restrict__ Wk,
                                                  float* __restrict__ PKT) {
    int h = blockIdx.x >> 6;
    int s = blockIdx.x & 63;
    int t = threadIdx.x;
    __shared__ float p_s[ND];
    p_s[t] = P[s * ND + t];
    __syncthreads();
    const float* wk = Wk + h * (ND * NL) + t;
    float acc = 0.f;
    #pragma unroll 8
    for (int d = 0; d < ND; ++d) acc = fmaf(p_s[d], wk[d * NL], acc);
    PKT[((size_t)h * NL + t) * NS + s] = acc;
}

// ---------------------------------------------------------------------------
// OK[h][b][l] = origin_b · Wk[h][:,l]  as f16 MFMA GEMM
// ---------------------------------------------------------------------------
__global__ __launch_bounds__(256) void ok_gemm(const float* __restrict__ x,
                                               const f16*   __restrict__ wh,
                                               float* __restrict__ OK) {
    int mblk = blockIdx.x >> 4;          // 32
    int nblk = blockIdx.x & 15;          // 16
    int b0 = mblk * 64;
    int h  = nblk >> 1;
    int l0 = (nblk & 1) * 128;
    int t = threadIdx.x;
    int w = t >> 6, lane = t & 63, c = lane & 15, g = lane >> 4;

    __shared__ f16 Ao[64 * APAD];
    #pragma unroll
    for (int it = 0; it < 16; ++it) {
        int idx4 = it * 256 + t;
        int s = idx4 >> 6, kq = idx4 & 63;
        float4 v = *(const float4*)(x + (size_t)(b0 + s) * (NSEQ * ND) + kq * 4);
        *(f16x4*)(&Ao[s * APAD + kq * 4]) = (f16x4){(f16)v.x, (f16)v.y, (f16)v.z, (f16)v.w};
    }
    __syncthreads();

    f32x4 acc[4][2];
    #pragma unroll
    for (int mt = 0; mt < 4; ++mt)
        #pragma unroll
        for (int nt = 0; nt < 2; ++nt) acc[mt][nt] = (f32x4){0.f, 0.f, 0.f, 0.f};

    const f16* bb = wh + ((size_t)((h * 3 + 2) * 256 + l0 + w * 32 + c)) * 256;
    #pragma unroll 2
    for (int kk = 0; kk < 8; ++kk) {
        int k0 = kk * 32 + g * 8;
        f16x8 af[4];
        #pragma unroll
        for (int mt = 0; mt < 4; ++mt)
            af[mt] = *(const f16x8*)(&Ao[(mt * 16 + c) * APAD + k0]);
        #pragma unroll
        for (int nt = 0; nt < 2; ++nt) {
            f16x8 bf = *(const f16x8*)(bb + nt * 16 * 256 + k0);
            #pragma unroll
            for (int mt = 0; mt < 4; ++mt)
                acc[mt][nt] = __builtin_amdgcn_mfma_f32_16x16x32_f16(af[mt], bf, acc[mt][nt], 0, 0, 0);
        }
    }
    #pragma unroll
    for (int mt = 0; mt < 4; ++mt)
        #pragma unroll
        for (int nt = 0; nt < 2; ++nt)
            #pragma unroll
            for (int r = 0; r < 4; ++r)
                OK[((size_t)h * NB + b0 + mt * 16 + g * 4 + r) * NL + l0 + w * 32 + nt * 16 + c]
                    = acc[mt][nt][r];
}

// ---------------------------------------------------------------------------
// Main fused kernel: no LDS; wave-private heads; SOFTWARE-PIPELINED chunks.
// 16 chunks of 16 l-cols per pass. Double-buffered accumulators: MFMA burst
// of chunk ci overlaps (in one straight-line region) the trans/VALU epilogue
// of chunk ci-1 — scheduler fills the matrix-pipe shadow with epilogue ops.
// ---------------------------------------------------------------------------
__global__ __launch_bounds__(256, 2) void attn_mfma(
        const f16*   __restrict__ xh,
        const f16*   __restrict__ wh,
        const float* __restrict__ W,
        const float* __restrict__ PKT,
        const float* __restrict__ OK,
        f16* __restrict__ res) {
    int b = blockIdx.x;
    int t = threadIdx.x;
    int w    = t >> 6;
    int lane = t & 63;
    int c = lane & 15;
    int g = lane >> 4;

    // --- A fragments in registers: af[mt][kk] = xh[b][mt*16+c][kk*32+g*8] --
    f16x8 af[4][8];
    const f16* xb = xh + (size_t)b * 16384 + c * 256 + g * 8;
    #pragma unroll
    for (int mt = 0; mt < 4; ++mt)
        #pragma unroll
        for (int kk = 0; kk < 8; ++kk)
            af[mt][kk] = *(const f16x8*)(xb + mt * 16 * 256 + kk * 32);

    int rot  = b & 15;                   // chunk-phase rotation (decorrelate blocks)
    int hrot = (b >> 4) & 1;

    #pragma unroll 1
    for (int hh = 0; hh < 2; ++hh) {
        int h = w * 2 + ((hh + hrot) & 1);
        const f16* bqbase = wh + ((size_t)((h * 3 + 0) * 256 + c)) * 256 + g * 8;
        const f16* bvbase = wh + ((size_t)((h * 3 + 1) * 256 + c)) * 256 + g * 8;
        const float* Wp   = W + h * NL + c;
        const float* OKp  = OK + ((size_t)h * NB + b) * NL + c;
        const float* PKp  = PKT + ((size_t)h * NL + c) * NS + g * 4;

        float part[4][4];                // [mt][r] -> s = mt*16 + g*4 + r
        #pragma unroll
        for (int mt = 0; mt < 4; ++mt)
            #pragma unroll
            for (int r = 0; r < 4; ++r) part[mt][r] = 0.f;

        f32x4 accP[2][4];                // ping-pong accumulators [pi][mt]

        // ================= pass 1: q-GEMM + edge, pipelined ================
        #pragma unroll
        for (int ci = 0; ci <= 16; ++ci) {
            int pi = ci & 1;
            if (ci < 16) {               // MFMA burst for chunk ci -> accP[pi]
                int ch = (ci + rot) & 15;
                const f16* bq = bqbase + (size_t)(ch * 16) * 256;
                #pragma unroll
                for (int mt = 0; mt < 4; ++mt) accP[pi][mt] = (f32x4){0.f, 0.f, 0.f, 0.f};
                #pragma unroll
                for (int kk = 0; kk < 8; ++kk) {
                    f16x8 bf = *(const f16x8*)(bq + kk * 32);
                    #pragma unroll
                    for (int mt = 0; mt < 4; ++mt)
                        accP[pi][mt] = __builtin_amdgcn_mfma_f32_16x16x32_f16(af[mt][kk], bf, accP[pi][mt], 0, 0, 0);
                }
            }
            if (ci > 0) {                // epilogue for chunk ci-1 <- accP[pi^1]
                int qi = pi ^ 1;
                int chp = (ci - 1 + rot) & 15;
                int lo = chp * 16;
                float wl  = Wp[lo];
                float okv = OKp[lo];
                const float* pkcol = PKp + (size_t)lo * NS;
                #pragma unroll
                for (int mt = 0; mt < 4; ++mt) {
                    float4 pk4 = *(const float4*)(pkcol + mt * 16);
                    float pks[4] = {pk4.x, pk4.y, pk4.z, pk4.w};
                    #pragma unroll
                    for (int r = 0; r < 4; ++r) {
                        float qs = sigmoidf_(accP[qi][mt][r]);
                        float ks = sigmoidf_(okv + pks[r]);
                        part[mt][r] = fmaf(cos01_(ks * qs), wl, part[mt][r]);
                    }
                }
            }
        }

        // ======== v-pass chunk 0 MFMA issued BEFORE softmax (shadow) =======
        {
            const f16* bv = bvbase + (size_t)((rot & 15) * 16) * 256;
            #pragma unroll
            for (int mt = 0; mt < 4; ++mt) accP[0][mt] = (f32x4){0.f, 0.f, 0.f, 0.f};
            #pragma unroll
            for (int kk = 0; kk < 8; ++kk) {
                f16x8 bf = *(const f16x8*)(bv + kk * 32);
                #pragma unroll
                for (int mt = 0; mt < 4; ++mt)
                    accP[0][mt] = __builtin_amdgcn_mfma_f32_16x16x32_f16(af[mt][kk], bf, accP[0][mt], 0, 0, 0);
            }
        }

        // ---- in-wave score reduction over c, softmax over 64 s -----------
        #pragma unroll
        for (int mt = 0; mt < 4; ++mt)
            #pragma unroll
            for (int r = 0; r < 4; ++r) {
                float v = part[mt][r];
                v += __shfl_xor(v, 1, 64);
                v += __shfl_xor(v, 2, 64);
                v += __shfl_xor(v, 4, 64);
                v += __shfl_xor(v, 8, 64);
                part[mt][r] = v;         // score[s], uniform over c
            }
        float m = part[0][0];
        #pragma unroll
        for (int mt = 0; mt < 4; ++mt)
            #pragma unroll
            for (int r = 0; r < 4; ++r) m = fmaxf(m, part[mt][r]);
        m = fmaxf(m, __shfl_xor(m, 16, 64));
        m = fmaxf(m, __shfl_xor(m, 32, 64));
        float ssum = 0.f;
        #pragma unroll
        for (int mt = 0; mt < 4; ++mt)
            #pragma unroll
            for (int r = 0; r < 4; ++r) {
                float e = __expf(part[mt][r] - m);
                part[mt][r] = e;
                ssum += e;
            }
        ssum += __shfl_xor(ssum, 16, 64);
        ssum += __shfl_xor(ssum, 32, 64);
        float rinv = __builtin_amdgcn_rcpf(ssum);
        #pragma unroll
        for (int mt = 0; mt < 4; ++mt)
            #pragma unroll
            for (int r = 0; r < 4; ++r) part[mt][r] *= rinv;   // p_s

        // ================= pass 2: v-GEMM + weighted sum, pipelined ========
        #pragma unroll
        for (int ci = 1; ci <= 16; ++ci) {
            int pi = ci & 1;
            if (ci < 16) {               // MFMA burst for chunk ci -> accP[pi]
                int ch = (ci + rot) & 15;
                const f16* bv = bvbase + (size_t)(ch * 16) * 256;
                #pragma unroll
                for (int mt = 0; mt < 4; ++mt) accP[pi][mt] = (f32x4){0.f, 0.f, 0.f, 0.f};
                #pragma unroll
                for (int kk = 0; kk < 8; ++kk) {
                    f16x8 bf = *(const f16x8*)(bv + kk * 32);
                    #pragma unroll
                    for (int mt = 0; mt < 4; ++mt)
                        accP[pi][mt] = __builtin_amdgcn_mfma_f32_16x16x32_f16(af[mt][kk], bf, accP[pi][mt], 0, 0, 0);
                }
            }
            {                            // epilogue for chunk ci-1 <- accP[pi^1]
                int qi = pi ^ 1;
                int chp = (ci - 1 + rot) & 15;
                float v = 0.f;
                #pragma unroll
                for (int mt = 0; mt < 4; ++mt)
                    #pragma unroll
                    for (int r = 0; r < 4; ++r)
                        v = fmaf(part[mt][r], sigmoidf_(accP[qi][mt][r]), v);
                v += __shfl_xor(v, 16, 64);
                v += __shfl_xor(v, 32, 64);
                if (g == 0)
                    res[(size_t)b * 2048 + h * NL + chp * 16 + c] = (f16)v;
            }
        }
    }
}

// ---------------------------------------------------------------------------
// out GEMM: out[b][0:256] = sigmoid(res[b] @ O)  (f16 MFMA, K=2048)
// ---------------------------------------------------------------------------
__global__ __launch_bounds__(256) void out_gemm(
        const float* __restrict__ x,
        const f16*   __restrict__ res,
        const f16*   __restrict__ OT,
        float* __restrict__ out) {
    int mblk = blockIdx.x >> 1;          // 64 tiles of 32 rows
    int nblk = blockIdx.x & 1;           // 2 tiles of 128 cols
    int b0 = mblk * 32;
    int t  = threadIdx.x;
    int w    = t >> 6;
    int lane = t & 63;
    int c = lane & 15;
    int g = lane >> 4;

    __shared__ f16 Ao[32 * APAD];

    f32x4 acc[2][2];
    #pragma unroll
    for (int mt = 0; mt < 2; ++mt)
        #pragma unroll
        for (int nt = 0; nt < 2; ++nt) acc[mt][nt] = (f32x4){0.f, 0.f, 0.f, 0.f};

    for (int chunk = 0; chunk < 8; ++chunk) {
        int kbase = chunk * 256;
        __syncthreads();
        #pragma unroll
        for (int it = 0; it < 4; ++it) {
            int id  = it * 256 + t;
            int row = id >> 5;
            int kc  = (id & 31) << 3;
            *(f16x8*)(&Ao[row * APAD + kc]) =
                *(const f16x8*)(res + (size_t)(b0 + row) * 2048 + kbase + kc);
        }
        __syncthreads();
        #pragma unroll
        for (int kk = 0; kk < 8; ++kk) {
            int k0 = kk * 32 + g * 8;
            f16x8 af[2];
            #pragma unroll
            for (int mt = 0; mt < 2; ++mt)
                af[mt] = *(const f16x8*)(&Ao[(mt * 16 + c) * APAD + k0]);
            #pragma unroll
            for (int nt = 0; nt < 2; ++nt) {
                f16x8 bf = *(const f16x8*)(OT + (size_t)(nblk * 128 + w * 32 + nt * 16 + c) * 2048 + kbase + k0);
                #pragma unroll
                for (int mt = 0; mt < 2; ++mt)
                    acc[mt][nt] = __builtin_amdgcn_mfma_f32_16x16x32_f16(af[mt], bf, acc[mt][nt], 0, 0, 0);
            }
        }
    }
    #pragma unroll
    for (int mt = 0; mt < 2; ++mt)
        #pragma unroll
        for (int nt = 0; nt < 2; ++nt)
            #pragma unroll
            for (int r = 0; r < 4; ++r) {
                int row = mt * 16 + g * 4 + r;
                int col = nblk * 128 + w * 32 + nt * 16 + c;
                out[(size_t)(b0 + row) * 512 + col] = sigmoidf_(acc[mt][nt][r]);
            }
    if (nblk == 1) {                     // origin passthrough for these 32 rows
        for (int r2 = 0; r2 < 32; ++r2)
            out[(size_t)(b0 + r2) * 512 + 256 + t] = x[(size_t)(b0 + r2) * (NSEQ * ND) + t];
    }
}

// ---------------------------------------------------------------------------
extern "C" void kernel_launch(void* const* d_in, const int* in_sizes, int n_in,
                              void* d_out, int out_size, void* d_ws, size_t ws_size,
                              hipStream_t stream) {
    const float* x    = (const float*)d_in[0];
    const float* Wq   = (const float*)d_in[1];
    const float* Wk   = (const float*)d_in[2];
    const float* Wv   = (const float*)d_in[3];
    const float* W    = (const float*)d_in[4];
    const float* O    = (const float*)d_in[5];
    const float* P    = (const float*)d_in[6];
    // d_in[7] = bias: unused — softmax is invariant to the bias*sum(W) shift
    float* out = (float*)d_out;

    // ws carve: wh 3MB | OT 1MB | PKT 512KB | OK 16MB | res 8MB | xh 32MB
    char* wsb = (char*)d_ws;
    f16*   wh  = (f16*)wsb;                       // 3*8*256*256 f16 = 3145728 B
    f16*   OT  = (f16*)(wsb + 3145728);           // 256*2048 f16   = 1048576 B
    float* PKT = (float*)(wsb + 4194304);         // 8*256*64 f32   = 524288 B
    float* OK  = (float*)(wsb + 4718592);         // 8*2048*256 f32 = 16777216 B
    f16*   res = (f16*)(wsb + 21495808);          // 2048*2048 f16  = 8388608 B
    f16*   xh  = (f16*)(wsb + 29884416);          // 2048*64*256 f16 = 33554432 B

    xh_kernel<<<16384, 256, 0, stream>>>(x, xh);
    wh_kernel<<<384, 256, 0, stream>>>(Wq, Wv, Wk, wh);
    ot_kernel<<<256, 256, 0, stream>>>(O, OT);
    pkt_kernel<<<NH * NS, 256, 0, stream>>>(P, Wk, PKT);
    ok_gemm<<<512, 256, 0, stream>>>(x, wh, OK);
    attn_mfma<<<NB, 256, 0, stream>>>(xh, wh, W, PKT, OK, res);
    out_gemm<<<128, 256, 0, stream>>>(x, res, OT, out);
}